// Round 3
// baseline (221.575 us; speedup 1.0000x reference)
//
#include <hip/hip_runtime.h>

#define BATCH 8192
#define IN_F 4096
#define OUT_F 4096

typedef float f4 __attribute__((ext_vector_type(4)));

// One WAVE per row, fully fused: read row (NT) -> in-wave butterfly reduce
// -> scale w -> NT store row. No __syncthreads, no LDS, no workspace.
// 8192 rows / 4 waves per block = 2048 blocks; 32 waves/CU; read and write
// streams overlap at the HBM controller (mixed-stream ceiling ~6.3 TB/s).
__global__ __launch_bounds__(256) void
rank1_fused_kernel(const float* __restrict__ x, const float* __restrict__ w,
                   float* __restrict__ out) {
    const int wave = threadIdx.x >> 6;
    const int lane = threadIdx.x & 63;
    const int row  = (blockIdx.x << 2) + wave;

    // ---- read + reduce: 1024 f4 per row, 16 f4 per lane, NT loads ----
    const f4* x4 = reinterpret_cast<const f4*>(x + (size_t)row * IN_F);
    float s0 = 0.f, s1 = 0.f, s2 = 0.f, s3 = 0.f;
#pragma unroll
    for (int j = 0; j < 16; j += 4) {
        f4 a = __builtin_nontemporal_load(&x4[(j + 0) * 64 + lane]);
        f4 b = __builtin_nontemporal_load(&x4[(j + 1) * 64 + lane]);
        f4 c = __builtin_nontemporal_load(&x4[(j + 2) * 64 + lane]);
        f4 d = __builtin_nontemporal_load(&x4[(j + 3) * 64 + lane]);
        s0 += (a.x + a.y) + (a.z + a.w);
        s1 += (b.x + b.y) + (b.z + b.w);
        s2 += (c.x + c.y) + (c.z + c.w);
        s3 += (d.x + d.y) + (d.z + d.w);
    }
    float s = (s0 + s1) + (s2 + s3);

    // butterfly: every lane ends with the full row sum (no broadcast step)
#pragma unroll
    for (int off = 1; off < 64; off <<= 1)
        s += __shfl_xor(s, off, 64);

    // ---- scale + write: w is L1-hot (16 KiB shared by all waves) ----
    const f4* w4 = reinterpret_cast<const f4*>(w);
    f4* o4 = reinterpret_cast<f4*>(out + (size_t)row * OUT_F);
#pragma unroll
    for (int j = 0; j < 16; j += 4) {
        f4 wa = w4[(j + 0) * 64 + lane];
        f4 wb = w4[(j + 1) * 64 + lane];
        f4 wc = w4[(j + 2) * 64 + lane];
        f4 wd = w4[(j + 3) * 64 + lane];
        f4 oa, ob, oc, od;
        oa.x = s * wa.x; oa.y = s * wa.y; oa.z = s * wa.z; oa.w = s * wa.w;
        ob.x = s * wb.x; ob.y = s * wb.y; ob.z = s * wb.z; ob.w = s * wb.w;
        oc.x = s * wc.x; oc.y = s * wc.y; oc.z = s * wc.z; oc.w = s * wc.w;
        od.x = s * wd.x; od.y = s * wd.y; od.z = s * wd.z; od.w = s * wd.w;
        __builtin_nontemporal_store(oa, &o4[(j + 0) * 64 + lane]);
        __builtin_nontemporal_store(ob, &o4[(j + 1) * 64 + lane]);
        __builtin_nontemporal_store(oc, &o4[(j + 2) * 64 + lane]);
        __builtin_nontemporal_store(od, &o4[(j + 3) * 64 + lane]);
    }
}

extern "C" void kernel_launch(void* const* d_in, const int* in_sizes, int n_in,
                              void* d_out, int out_size, void* d_ws, size_t ws_size,
                              hipStream_t stream) {
    const float* x = (const float*)d_in[0];   // [8192, 4096] fp32
    const float* w = (const float*)d_in[1];   // [1, 4096] fp32
    float* out = (float*)d_out;               // [8192, 4096] fp32
    rank1_fused_kernel<<<BATCH / 4, 256, 0, stream>>>(x, w, out);
}